// Round 1
// baseline (764.692 us; speedup 1.0000x reference)
//
#include <hip/hip_runtime.h>
#include <math.h>

#define NN 100000
#define NE 1600000
#define D  64

__device__ __forceinline__ unsigned int fkey(float f) {
    unsigned int u = __float_as_uint(f);
    return (u & 0x80000000u) ? ~u : (u | 0x80000000u);
}
__device__ __forceinline__ float fdecode(unsigned int k) {
    unsigned int u = (k & 0x80000000u) ? (k & 0x7FFFFFFFu) : ~k;
    return __uint_as_float(u);
}

// ---------------- K0: init accum (=d_out), denom, maxkey ----------------
__global__ __launch_bounds__(256) void k_init(float* __restrict__ accum,
                                              float* __restrict__ denom,
                                              unsigned int* __restrict__ maxkey) {
    int i = blockIdx.x * blockDim.x + threadIdx.x;
    int stride = gridDim.x * blockDim.x;
    for (int t = i; t < NN * D; t += stride) accum[t] = 0.0f;
    for (int t = i; t < NN; t += stride) denom[t] = 0.0f;
    if (i == 0) *maxkey = 0u;
}

// ---------------- K1: per-node z norms (wave per node) ----------------
__global__ __launch_bounds__(256) void k_norms(const float* __restrict__ z,
                                               float* __restrict__ norms) {
    int wave = (blockIdx.x * blockDim.x + threadIdx.x) >> 6;
    int lane = threadIdx.x & 63;
    if (wave >= NN) return;
    float v = z[wave * D + lane];
    float s = v * v;
#pragma unroll
    for (int off = 32; off; off >>= 1) s += __shfl_xor(s, off);
    if (lane == 0) norms[wave] = sqrtf(s);
}

// ---------------- K2: per-edge logits + global max (wave per edge) ----------------
__global__ __launch_bounds__(256) void k_logits(const float* __restrict__ z,
                                                const int* __restrict__ ei,
                                                const float* __restrict__ norms,
                                                const float* __restrict__ alpha_p,
                                                const float* __restrict__ bias_p,
                                                float* __restrict__ logits,
                                                unsigned int* __restrict__ maxkey) {
    const float alpha = *alpha_p;
    const float bias = *bias_p;
    const int lane = threadIdx.x & 63;
    const int wpb = blockDim.x >> 6;
    int wave = blockIdx.x * wpb + (threadIdx.x >> 6);
    int nWaves = gridDim.x * wpb;
    float mloc = -3.4e38f;
    for (int e = wave; e < NE; e += nWaves) {
        int r = ei[e];
        int c = ei[NE + e];
        float zi = z[r * D + lane];
        float zj = z[c * D + lane];
        float s = zi * zj;
#pragma unroll
        for (int off = 32; off; off >>= 1) s += __shfl_xor(s, off);
        float den = fmaxf(norms[r] * norms[c], 1e-9f);
        float lg = alpha * (s / den) + bias;
        if (lane == 0) logits[e] = lg;
        mloc = fmaxf(mloc, lg);
    }
#pragma unroll
    for (int off = 32; off; off >>= 1) mloc = fmaxf(mloc, __shfl_xor(mloc, off));
    __shared__ unsigned int bmax;
    if (threadIdx.x == 0) bmax = 0u;
    __syncthreads();
    if (lane == 0) atomicMax(&bmax, fkey(mloc));
    __syncthreads();
    if (threadIdx.x == 0) atomicMax(maxkey, bmax);
}

// ---------------- K3: exp(logit - gmax), denom segment-sum ----------------
__global__ __launch_bounds__(256) void k_exp_denom(const int* __restrict__ ei,
                                                   float* __restrict__ logits,
                                                   float* __restrict__ denom,
                                                   const unsigned int* __restrict__ maxkey) {
    float gmax = fdecode(*maxkey);
    int i = blockIdx.x * blockDim.x + threadIdx.x;
    int stride = gridDim.x * blockDim.x;
    for (int e = i; e < NE; e += stride) {
        float ex = expf(logits[e] - gmax);
        logits[e] = ex;  // store exp in place
        atomicAdd(&denom[ei[e]], ex);
    }
}

// ---------------- K4: scatter messages (wave per edge) ----------------
__global__ __launch_bounds__(256) void k_scatter(const float* __restrict__ x,
                                                 const int* __restrict__ ei,
                                                 const float* __restrict__ logits,
                                                 const float* __restrict__ denom,
                                                 float* __restrict__ accum) {
    const int lane = threadIdx.x & 63;
    const int wpb = blockDim.x >> 6;
    int wave = blockIdx.x * wpb + (threadIdx.x >> 6);
    int nWaves = gridDim.x * wpb;
    for (int e = wave; e < NE; e += nWaves) {
        int r = ei[e];
        int c = ei[NE + e];
        float attn = logits[e] / (denom[r] + 1e-9f);
        float v = attn * x[c * D + lane];
        atomicAdd(&accum[r * D + lane], v);
    }
}

// ---------------- K5: out = accum @ W^T + b  (in place, wave per node) ----------------
__global__ __launch_bounds__(256) void k_linear(const float* __restrict__ W,
                                                const float* __restrict__ b,
                                                float* __restrict__ inout) {
    __shared__ float Wt[64 * 65];  // Wt[d*65 + j] = W[j*64 + d], padded
    __shared__ float bs[64];
    for (int i = threadIdx.x; i < 4096; i += blockDim.x) {
        Wt[(i & 63) * 65 + (i >> 6)] = W[i];
    }
    if (threadIdx.x < 64) bs[threadIdx.x] = b[threadIdx.x];
    __syncthreads();
    const int lane = threadIdx.x & 63;
    const int wpb = blockDim.x >> 6;
    int wave = blockIdx.x * wpb + (threadIdx.x >> 6);
    int nWaves = gridDim.x * wpb;
    for (int n = wave; n < NN; n += nWaves) {
        float a = inout[n * D + lane];
        float s = bs[lane];
#pragma unroll
        for (int d = 0; d < 64; ++d) {
            s = fmaf(__shfl(a, d), Wt[d * 65 + lane], s);
        }
        inout[n * D + lane] = s;
    }
}

extern "C" void kernel_launch(void* const* d_in, const int* in_sizes, int n_in,
                              void* d_out, int out_size, void* d_ws, size_t ws_size,
                              hipStream_t stream) {
    const float* x = (const float*)d_in[0];
    const int* ei = (const int*)d_in[1];  // [2, NE] int32
    const float* z = (const float*)d_in[2];
    const float* W = (const float*)d_in[3];
    const float* b = (const float*)d_in[4];
    const float* alpha = (const float*)d_in[5];
    const float* bias_edge = (const float*)d_in[6];
    float* accum = (float*)d_out;  // [NN, D]; accumulator, then final output in place

    // workspace layout
    char* ws = (char*)d_ws;
    float* norms = (float*)ws;                       // NN floats
    float* denom = (float*)(ws + NN * sizeof(float));      // NN floats
    float* logits = (float*)(ws + 2ull * NN * sizeof(float)); // NE floats
    unsigned int* maxkey = (unsigned int*)(ws + (2ull * NN + NE) * sizeof(float));

    k_init<<<2048, 256, 0, stream>>>(accum, denom, maxkey);
    k_norms<<<(NN * 64 + 255) / 256, 256, 0, stream>>>(z, norms);
    k_logits<<<2048, 256, 0, stream>>>(z, ei, norms, alpha, bias_edge, logits, maxkey);
    k_exp_denom<<<2048, 256, 0, stream>>>(ei, logits, denom, maxkey);
    k_scatter<<<4096, 256, 0, stream>>>(x, ei, logits, denom, accum);
    k_linear<<<2048, 256, 0, stream>>>(W, b, accum);
}

// Round 2
// 663.346 us; speedup vs baseline: 1.1528x; 1.1528x over previous
//
#include <hip/hip_runtime.h>
#include <math.h>

#define NN 100000
#define NE 1600000
#define D  64
#define NBLK 391  // ceil(NN/256)

__device__ __forceinline__ unsigned int fkey(float f) {
    unsigned int u = __float_as_uint(f);
    return (u & 0x80000000u) ? ~u : (u | 0x80000000u);
}
__device__ __forceinline__ float fdecode(unsigned int k) {
    unsigned int u = (k & 0x80000000u) ? (k & 0x7FFFFFFFu) : ~k;
    return __uint_as_float(u);
}

// ---------------- K0: init denom, cnt, maxkey ----------------
__global__ __launch_bounds__(256) void k_init(float* __restrict__ denom,
                                              int* __restrict__ cnt,
                                              unsigned int* __restrict__ maxkey) {
    int i = blockIdx.x * blockDim.x + threadIdx.x;
    int stride = gridDim.x * blockDim.x;
    for (int t = i; t < NN; t += stride) { denom[t] = 0.0f; cnt[t] = 0; }
    if (i == 0) *maxkey = 0u;
}

// ---------------- K1: per-node z norms (wave per node) ----------------
__global__ __launch_bounds__(256) void k_norms(const float* __restrict__ z,
                                               float* __restrict__ norms) {
    int wave = (blockIdx.x * blockDim.x + threadIdx.x) >> 6;
    int lane = threadIdx.x & 63;
    if (wave >= NN) return;
    float v = z[wave * D + lane];
    float s = v * v;
#pragma unroll
    for (int off = 32; off; off >>= 1) s += __shfl_xor(s, off);
    if (lane == 0) norms[wave] = sqrtf(s);
}

// ---------------- K2: per-edge logits + row counts + global max ----------------
__global__ __launch_bounds__(256) void k_logits(const float* __restrict__ z,
                                                const int* __restrict__ ei,
                                                const float* __restrict__ norms,
                                                const float* __restrict__ alpha_p,
                                                const float* __restrict__ bias_p,
                                                float* __restrict__ logits,
                                                int* __restrict__ cnt,
                                                unsigned int* __restrict__ maxkey) {
    const float alpha = *alpha_p;
    const float bias = *bias_p;
    const int lane = threadIdx.x & 63;
    const int wpb = blockDim.x >> 6;
    int wave = blockIdx.x * wpb + (threadIdx.x >> 6);
    int nWaves = gridDim.x * wpb;
    float mloc = -3.4e38f;
    for (int e = wave; e < NE; e += nWaves) {
        int r = ei[e];
        int c = ei[NE + e];
        float zi = z[r * D + lane];
        float zj = z[c * D + lane];
        float s = zi * zj;
#pragma unroll
        for (int off = 32; off; off >>= 1) s += __shfl_xor(s, off);
        float den = fmaxf(norms[r] * norms[c], 1e-9f);
        float lg = alpha * (s / den) + bias;
        if (lane == 0) {
            logits[e] = lg;
            atomicAdd(&cnt[r], 1);
        }
        mloc = fmaxf(mloc, lg);
    }
#pragma unroll
    for (int off = 32; off; off >>= 1) mloc = fmaxf(mloc, __shfl_xor(mloc, off));
    __shared__ unsigned int bmax;
    if (threadIdx.x == 0) bmax = 0u;
    __syncthreads();
    if (lane == 0) atomicMax(&bmax, fkey(mloc));
    __syncthreads();
    if (threadIdx.x == 0) atomicMax(maxkey, bmax);
}

// ---------------- scan: exclusive prefix sum of cnt -> row_start, cursor ----------------
__global__ __launch_bounds__(256) void k_scan1(const int* __restrict__ cnt,
                                               int* __restrict__ inc,
                                               int* __restrict__ bsum) {
    __shared__ int sh[256];
    int gid = blockIdx.x * 256 + threadIdx.x;
    int v = (gid < NN) ? cnt[gid] : 0;
    sh[threadIdx.x] = v;
    __syncthreads();
    for (int off = 1; off < 256; off <<= 1) {
        int t = (threadIdx.x >= off) ? sh[threadIdx.x - off] : 0;
        __syncthreads();
        sh[threadIdx.x] += t;
        __syncthreads();
    }
    if (gid < NN) inc[gid] = sh[threadIdx.x];
    if (threadIdx.x == 255) bsum[blockIdx.x] = sh[255];
}

__global__ __launch_bounds__(512) void k_scan2(int* __restrict__ bsum) {
    __shared__ int sh[512];
    int v = (threadIdx.x < NBLK) ? bsum[threadIdx.x] : 0;
    sh[threadIdx.x] = v;
    __syncthreads();
    for (int off = 1; off < 512; off <<= 1) {
        int t = (threadIdx.x >= off) ? sh[threadIdx.x - off] : 0;
        __syncthreads();
        sh[threadIdx.x] += t;
        __syncthreads();
    }
    if (threadIdx.x < NBLK) bsum[threadIdx.x] = sh[threadIdx.x] - v;  // exclusive
}

__global__ __launch_bounds__(256) void k_scan3(const int* __restrict__ cnt,
                                               const int* __restrict__ inc,
                                               const int* __restrict__ bsum,
                                               int* __restrict__ row_start,
                                               int* __restrict__ cursor) {
    int gid = blockIdx.x * 256 + threadIdx.x;
    if (gid < NN) {
        int ex = inc[gid] - cnt[gid] + bsum[blockIdx.x];
        row_start[gid] = ex;
        cursor[gid] = ex;
    }
}

// ---------------- K_fill: exp + denom + CSR placement ----------------
__global__ __launch_bounds__(256) void k_fill(const int* __restrict__ ei,
                                              const float* __restrict__ logits,
                                              const unsigned int* __restrict__ maxkey,
                                              float* __restrict__ denom,
                                              int* __restrict__ cursor,
                                              int2* __restrict__ packed) {
    float gmax = fdecode(*maxkey);
    int i = blockIdx.x * blockDim.x + threadIdx.x;
    int stride = gridDim.x * blockDim.x;
    for (int e = i; e < NE; e += stride) {
        int r = ei[e];
        int c = ei[NE + e];
        float ex = expf(logits[e] - gmax);
        atomicAdd(&denom[r], ex);
        int pos = atomicAdd(&cursor[r], 1);
        packed[pos] = make_int2(c, __float_as_int(ex));
    }
}

// ---------------- K_gather: per-node gather + denom div + W^T + b ----------------
__global__ __launch_bounds__(256) void k_gather(const int2* __restrict__ packed,
                                                const int* __restrict__ row_start,
                                                const int* __restrict__ cnt,
                                                const float* __restrict__ denom,
                                                const float* __restrict__ x,
                                                const float* __restrict__ W,
                                                const float* __restrict__ b,
                                                float* __restrict__ out) {
    __shared__ float Wt[64 * 65];  // Wt[d*65 + j] = W[j*64 + d]
    __shared__ float bs[64];
    for (int i = threadIdx.x; i < 4096; i += blockDim.x) {
        Wt[(i & 63) * 65 + (i >> 6)] = W[i];
    }
    if (threadIdx.x < 64) bs[threadIdx.x] = b[threadIdx.x];
    __syncthreads();
    const int lane = threadIdx.x & 63;
    const int wpb = blockDim.x >> 6;
    int wave = blockIdx.x * wpb + (threadIdx.x >> 6);
    int nWaves = gridDim.x * wpb;
    for (int n = wave; n < NN; n += nWaves) {
        int s0 = row_start[n];
        int c = cnt[n];
        float acc = 0.0f;
        for (int base = 0; base < c; base += 64) {
            int m = min(64, c - base);
            int idx = base + lane;
            int2 p = (idx < c) ? packed[s0 + idx] : make_int2(0, 0);
            for (int j = 0; j < m; ++j) {
                int col = __shfl(p.x, j);
                float ex = __shfl(__int_as_float(p.y), j);
                acc = fmaf(ex, x[col * D + lane], acc);
            }
        }
        float a = acc / (denom[n] + 1e-9f);
        float sres = bs[lane];
#pragma unroll
        for (int d = 0; d < 64; ++d) {
            sres = fmaf(__shfl(a, d), Wt[d * 65 + lane], sres);
        }
        out[n * D + lane] = sres;
    }
}

extern "C" void kernel_launch(void* const* d_in, const int* in_sizes, int n_in,
                              void* d_out, int out_size, void* d_ws, size_t ws_size,
                              hipStream_t stream) {
    const float* x = (const float*)d_in[0];
    const int* ei = (const int*)d_in[1];  // [2, NE] int32
    const float* z = (const float*)d_in[2];
    const float* W = (const float*)d_in[3];
    const float* b = (const float*)d_in[4];
    const float* alpha = (const float*)d_in[5];
    const float* bias_edge = (const float*)d_in[6];
    float* out = (float*)d_out;  // [NN, D]

    // workspace layout
    char* ws = (char*)d_ws;
    size_t off = 0;
    float* norms = (float*)(ws + off); off += (size_t)NN * 4;
    float* denom = (float*)(ws + off); off += (size_t)NN * 4;
    int* cnt = (int*)(ws + off); off += (size_t)NN * 4;
    int* inc = (int*)(ws + off); off += (size_t)NN * 4;
    int* row_start = (int*)(ws + off); off += (size_t)NN * 4;
    int* cursor = (int*)(ws + off); off += (size_t)NN * 4;
    int* bsum = (int*)(ws + off); off += 512 * 4;
    unsigned int* maxkey = (unsigned int*)(ws + off); off += 64;
    float* logits = (float*)(ws + off); off += (size_t)NE * 4;
    int2* packed = (int2*)(ws + off); off += (size_t)NE * 8;

    k_init<<<512, 256, 0, stream>>>(denom, cnt, maxkey);
    k_norms<<<(NN * 64 + 255) / 256, 256, 0, stream>>>(z, norms);
    k_logits<<<2048, 256, 0, stream>>>(z, ei, norms, alpha, bias_edge, logits, cnt, maxkey);
    k_scan1<<<NBLK, 256, 0, stream>>>(cnt, inc, bsum);
    k_scan2<<<1, 512, 0, stream>>>(bsum);
    k_scan3<<<NBLK, 256, 0, stream>>>(cnt, inc, bsum, row_start, cursor);
    k_fill<<<2048, 256, 0, stream>>>(ei, logits, maxkey, denom, cursor, packed);
    k_gather<<<2048, 256, 0, stream>>>(packed, row_start, cnt, denom, x, W, b, out);
}

// Round 3
// 529.772 us; speedup vs baseline: 1.4434x; 1.2521x over previous
//
#include <hip/hip_runtime.h>
#include <hip/hip_fp16.h>
#include <math.h>

#define NN 100000
#define NE 1600000
#define D  64
#define NBLK 391  // ceil(NN/256)

// ---------------- K_prep: zn = z/||z|| and x, both fp16, interleaved [n][128]; cnt=0 ----------------
__global__ __launch_bounds__(256) void k_prep(const float* __restrict__ z,
                                              const float* __restrict__ x,
                                              __half* __restrict__ zxh,
                                              int* __restrict__ cnt) {
    int wave = (blockIdx.x * blockDim.x + threadIdx.x) >> 6;
    int lane = threadIdx.x & 63;
    if (wave >= NN) return;
    float v = z[wave * D + lane];
    float s = v * v;
#pragma unroll
    for (int off = 32; off; off >>= 1) s += __shfl_xor(s, off);
    float inv = 1.0f / sqrtf(fmaxf(s, 1e-18f));
    zxh[wave * 128 + lane] = __float2half(v * inv);
    zxh[wave * 128 + 64 + lane] = __float2half(x[wave * D + lane]);
    if (lane == 0) cnt[wave] = 0;
}

// ---------------- K_count: edges per destination row ----------------
__global__ __launch_bounds__(256) void k_count(const int* __restrict__ ei,
                                               int* __restrict__ cnt) {
    int i = blockIdx.x * blockDim.x + threadIdx.x;
    int stride = gridDim.x * blockDim.x;
    for (int e = i; e < NE; e += stride) atomicAdd(&cnt[ei[e]], 1);
}

// ---------------- scan: exclusive prefix sum of cnt -> row_start, cursor ----------------
__global__ __launch_bounds__(256) void k_scan1(const int* __restrict__ cnt,
                                               int* __restrict__ inc,
                                               int* __restrict__ bsum) {
    __shared__ int sh[256];
    int gid = blockIdx.x * 256 + threadIdx.x;
    int v = (gid < NN) ? cnt[gid] : 0;
    sh[threadIdx.x] = v;
    __syncthreads();
    for (int off = 1; off < 256; off <<= 1) {
        int t = (threadIdx.x >= off) ? sh[threadIdx.x - off] : 0;
        __syncthreads();
        sh[threadIdx.x] += t;
        __syncthreads();
    }
    if (gid < NN) inc[gid] = sh[threadIdx.x];
    if (threadIdx.x == 255) bsum[blockIdx.x] = sh[255];
}

__global__ __launch_bounds__(512) void k_scan2(int* __restrict__ bsum) {
    __shared__ int sh[512];
    int v = (threadIdx.x < NBLK) ? bsum[threadIdx.x] : 0;
    sh[threadIdx.x] = v;
    __syncthreads();
    for (int off = 1; off < 512; off <<= 1) {
        int t = (threadIdx.x >= off) ? sh[threadIdx.x - off] : 0;
        __syncthreads();
        sh[threadIdx.x] += t;
        __syncthreads();
    }
    if (threadIdx.x < NBLK) bsum[threadIdx.x] = sh[threadIdx.x] - v;  // exclusive
}

__global__ __launch_bounds__(256) void k_scan3(const int* __restrict__ cnt,
                                               const int* __restrict__ inc,
                                               const int* __restrict__ bsum,
                                               int* __restrict__ row_start,
                                               int* __restrict__ cursor) {
    int gid = blockIdx.x * 256 + threadIdx.x;
    if (gid < NN) {
        int ex = inc[gid] - cnt[gid] + bsum[blockIdx.x];
        row_start[gid] = ex;
        cursor[gid] = ex;
    }
}

// ---------------- K_place: CSR col fill ----------------
__global__ __launch_bounds__(256) void k_place(const int* __restrict__ ei,
                                               int* __restrict__ cursor,
                                               int* __restrict__ colidx) {
    int i = blockIdx.x * blockDim.x + threadIdx.x;
    int stride = gridDim.x * blockDim.x;
    for (int e = i; e < NE; e += stride) {
        int r = ei[e];
        int c = ei[NE + e];
        int pos = atomicAdd(&cursor[r], 1);
        colidx[pos] = c;
    }
}

// ---------------- K_main: per-node fused corr->exp->softmax->gather->linear ----------------
__global__ __launch_bounds__(256) void k_main(const __half* __restrict__ zxh,
                                              const int* __restrict__ colidx,
                                              const int* __restrict__ row_start,
                                              const int* __restrict__ cnt,
                                              const float* __restrict__ W,
                                              const float* __restrict__ b,
                                              const float* __restrict__ alpha_p,
                                              const float* __restrict__ bias_p,
                                              float* __restrict__ out) {
    __shared__ float Wt[64 * 65];  // Wt[d*65 + j] = W[j*64 + d]
    __shared__ float bs[64];
    for (int i = threadIdx.x; i < 4096; i += blockDim.x) {
        Wt[(i & 63) * 65 + (i >> 6)] = W[i];
    }
    if (threadIdx.x < 64) bs[threadIdx.x] = b[threadIdx.x];
    __syncthreads();
    const float alpha = *alpha_p;
    const float bias = *bias_p;
    const float Mest = fabsf(alpha) + bias;  // >= max logit since |corr| <= 1
    const int lane = threadIdx.x & 63;
    const int wpb = blockDim.x >> 6;
    int wave = blockIdx.x * wpb + (threadIdx.x >> 6);
    int nWaves = gridDim.x * wpb;
    for (int n = wave; n < NN; n += nWaves) {
        float zi = __half2float(zxh[n * 128 + lane]);
        int s0 = row_start[n];
        int c = cnt[n];
        float acc = 0.0f;
        float dsum = 0.0f;
        for (int base = 0; base < c; base += 64) {
            int m = min(64, c - base);
            int idx = base + lane;
            int cc = (idx < c) ? colidx[s0 + idx] : 0;
            for (int j = 0; j < m; ++j) {
                int col = __shfl(cc, j);
                float zj = __half2float(zxh[col * 128 + lane]);
                float t = zi * zj;
#pragma unroll
                for (int off = 32; off; off >>= 1) t += __shfl_xor(t, off);
                float ex = __expf(alpha * t + bias - Mest);
                dsum += ex;
                acc = fmaf(ex, __half2float(zxh[col * 128 + 64 + lane]), acc);
            }
        }
        float a = acc / (dsum + 1e-9f);
        float sres = bs[lane];
#pragma unroll
        for (int d = 0; d < 64; ++d) {
            sres = fmaf(__shfl(a, d), Wt[d * 65 + lane], sres);
        }
        out[n * D + lane] = sres;
    }
}

extern "C" void kernel_launch(void* const* d_in, const int* in_sizes, int n_in,
                              void* d_out, int out_size, void* d_ws, size_t ws_size,
                              hipStream_t stream) {
    const float* x = (const float*)d_in[0];
    const int* ei = (const int*)d_in[1];  // [2, NE] int32
    const float* z = (const float*)d_in[2];
    const float* W = (const float*)d_in[3];
    const float* b = (const float*)d_in[4];
    const float* alpha = (const float*)d_in[5];
    const float* bias_edge = (const float*)d_in[6];
    float* out = (float*)d_out;  // [NN, D]

    // workspace layout
    char* ws = (char*)d_ws;
    size_t off = 0;
    __half* zxh = (__half*)(ws + off); off += (size_t)NN * 128 * 2;   // 25.6 MB
    int* colidx = (int*)(ws + off); off += (size_t)NE * 4;            // 6.4 MB
    int* cnt = (int*)(ws + off); off += (size_t)NN * 4;
    int* inc = (int*)(ws + off); off += (size_t)NN * 4;
    int* row_start = (int*)(ws + off); off += (size_t)NN * 4;
    int* cursor = (int*)(ws + off); off += (size_t)NN * 4;
    int* bsum = (int*)(ws + off); off += 512 * 4;

    k_prep<<<(NN * 64 + 255) / 256, 256, 0, stream>>>(z, x, zxh, cnt);
    k_count<<<2048, 256, 0, stream>>>(ei, cnt);
    k_scan1<<<NBLK, 256, 0, stream>>>(cnt, inc, bsum);
    k_scan2<<<1, 512, 0, stream>>>(bsum);
    k_scan3<<<NBLK, 256, 0, stream>>>(cnt, inc, bsum, row_start, cursor);
    k_place<<<2048, 256, 0, stream>>>(ei, cursor, colidx);
    k_main<<<4096, 256, 0, stream>>>(zxh, colidx, row_start, cnt, W, b, alpha, bias_edge, out);
}

// Round 4
// 377.160 us; speedup vs baseline: 2.0275x; 1.4046x over previous
//
#include <hip/hip_runtime.h>
#include <hip/hip_fp16.h>
#include <math.h>

#define NN 100000
#define NE 1600000
#define D  64
#define NBLK 391  // ceil(NN/256)

// ---------------- K_prep: zn = z/||z|| and x, both fp16, interleaved [n][128]; cnt=0 ----------------
__global__ __launch_bounds__(256) void k_prep(const float* __restrict__ z,
                                              const float* __restrict__ x,
                                              __half* __restrict__ zxh,
                                              int* __restrict__ cnt) {
    int wave = (blockIdx.x * blockDim.x + threadIdx.x) >> 6;
    int lane = threadIdx.x & 63;
    if (wave >= NN) return;
    float v = z[wave * D + lane];
    float s = v * v;
#pragma unroll
    for (int off = 32; off; off >>= 1) s += __shfl_xor(s, off);
    float inv = 1.0f / sqrtf(fmaxf(s, 1e-18f));
    zxh[wave * 128 + lane] = __float2half(v * inv);
    zxh[wave * 128 + 64 + lane] = __float2half(x[wave * D + lane]);
    if (lane == 0) cnt[wave] = 0;
}

// ---------------- K_count: edges per destination row ----------------
__global__ __launch_bounds__(256) void k_count(const int* __restrict__ ei,
                                               int* __restrict__ cnt) {
    int i = blockIdx.x * blockDim.x + threadIdx.x;
    int stride = gridDim.x * blockDim.x;
    for (int e = i; e < NE; e += stride) atomicAdd(&cnt[ei[e]], 1);
}

// ---------------- scan: exclusive prefix sum of cnt -> row_start, cursor ----------------
__global__ __launch_bounds__(256) void k_scan1(const int* __restrict__ cnt,
                                               int* __restrict__ inc,
                                               int* __restrict__ bsum) {
    __shared__ int sh[256];
    int gid = blockIdx.x * 256 + threadIdx.x;
    int v = (gid < NN) ? cnt[gid] : 0;
    sh[threadIdx.x] = v;
    __syncthreads();
    for (int off = 1; off < 256; off <<= 1) {
        int t = (threadIdx.x >= off) ? sh[threadIdx.x - off] : 0;
        __syncthreads();
        sh[threadIdx.x] += t;
        __syncthreads();
    }
    if (gid < NN) inc[gid] = sh[threadIdx.x];
    if (threadIdx.x == 255) bsum[blockIdx.x] = sh[255];
}

__global__ __launch_bounds__(512) void k_scan2(int* __restrict__ bsum) {
    __shared__ int sh[512];
    int v = (threadIdx.x < NBLK) ? bsum[threadIdx.x] : 0;
    sh[threadIdx.x] = v;
    __syncthreads();
    for (int off = 1; off < 512; off <<= 1) {
        int t = (threadIdx.x >= off) ? sh[threadIdx.x - off] : 0;
        __syncthreads();
        sh[threadIdx.x] += t;
        __syncthreads();
    }
    if (threadIdx.x < NBLK) bsum[threadIdx.x] = sh[threadIdx.x] - v;  // exclusive
}

__global__ __launch_bounds__(256) void k_scan3(const int* __restrict__ cnt,
                                               const int* __restrict__ inc,
                                               const int* __restrict__ bsum,
                                               int* __restrict__ row_start,
                                               int* __restrict__ cursor) {
    int gid = blockIdx.x * 256 + threadIdx.x;
    if (gid < NN) {
        int ex = inc[gid] - cnt[gid] + bsum[blockIdx.x];
        row_start[gid] = ex;
        cursor[gid] = ex;
    }
}

// ---------------- K_place: CSR fill (col AND row per position) ----------------
__global__ __launch_bounds__(256) void k_place(const int* __restrict__ ei,
                                               int* __restrict__ cursor,
                                               int* __restrict__ colidx,
                                               int* __restrict__ rowidx) {
    int i = blockIdx.x * blockDim.x + threadIdx.x;
    int stride = gridDim.x * blockDim.x;
    for (int e = i; e < NE; e += stride) {
        int r = ei[e];
        int c = ei[NE + e];
        int pos = atomicAdd(&cursor[r], 1);
        colidx[pos] = c;
        rowidx[pos] = r;
    }
}

// ---------------- K_edges: one edge per LANE — in-lane dot + exp, zero cross-lane ops ----------------
__global__ __launch_bounds__(256) void k_edges(const __half* __restrict__ zxh,
                                               const int* __restrict__ rowidx,
                                               const int* __restrict__ colidx,
                                               const float* __restrict__ alpha_p,
                                               const float* __restrict__ bias_p,
                                               float* __restrict__ exv) {
    int p = blockIdx.x * 256 + threadIdx.x;
    if (p >= NE) return;
    const float alpha = *alpha_p;
    const float bias = *bias_p;
    const float Mest = fabsf(alpha) + bias;  // >= max logit since |corr| <= 1
    int r = rowidx[p];
    int c = colidx[p];
    const float4* zi4 = (const float4*)(zxh + (size_t)r * 128);
    const float4* zj4 = (const float4*)(zxh + (size_t)c * 128);
    float4 a[8], bb[8];
#pragma unroll
    for (int k = 0; k < 8; ++k) { a[k] = zi4[k]; bb[k] = zj4[k]; }
    float dot = 0.0f;
#pragma unroll
    for (int k = 0; k < 8; ++k) {
        const __half2* ha = (const __half2*)&a[k];
        const __half2* hb = (const __half2*)&bb[k];
#pragma unroll
        for (int q = 0; q < 4; ++q) {
            float2 fa = __half22float2(ha[q]);
            float2 fb = __half22float2(hb[q]);
            dot = fmaf(fa.x, fb.x, dot);
            dot = fmaf(fa.y, fb.y, dot);
        }
    }
    exv[p] = __expf(alpha * dot + bias - Mest);
}

// ---------------- K_gather: wave per node, broadcast+fma only, fused linear ----------------
__global__ __launch_bounds__(256) void k_gather(const __half* __restrict__ zxh,
                                                const int* __restrict__ colidx,
                                                const float* __restrict__ exv,
                                                const int* __restrict__ row_start,
                                                const int* __restrict__ cnt,
                                                const float* __restrict__ W,
                                                const float* __restrict__ b,
                                                float* __restrict__ out) {
    __shared__ float Wt[64 * 65];  // Wt[d*65 + j] = W[j*64 + d]
    __shared__ float bs[64];
    for (int i = threadIdx.x; i < 4096; i += blockDim.x) {
        Wt[(i & 63) * 65 + (i >> 6)] = W[i];
    }
    if (threadIdx.x < 64) bs[threadIdx.x] = b[threadIdx.x];
    __syncthreads();
    const int lane = threadIdx.x & 63;
    int n = (blockIdx.x * blockDim.x + threadIdx.x) >> 6;  // one wave per node
    if (n >= NN) return;
    int s0 = row_start[n];
    int c = cnt[n];
    float acc = 0.0f;
    float dsum = 0.0f;
    for (int base = 0; base < c; base += 64) {
        int m = min(64, c - base);
        int idx = base + lane;
        int cc = (idx < c) ? colidx[s0 + idx] : 0;
        float ev = (idx < c) ? exv[s0 + idx] : 0.0f;
        int evi = __float_as_int(ev);
        int j = 0;
        for (; j + 4 <= m; j += 4) {
            int c0 = __builtin_amdgcn_readlane(cc, j);
            int c1 = __builtin_amdgcn_readlane(cc, j + 1);
            int c2 = __builtin_amdgcn_readlane(cc, j + 2);
            int c3 = __builtin_amdgcn_readlane(cc, j + 3);
            float e0 = __int_as_float(__builtin_amdgcn_readlane(evi, j));
            float e1 = __int_as_float(__builtin_amdgcn_readlane(evi, j + 1));
            float e2 = __int_as_float(__builtin_amdgcn_readlane(evi, j + 2));
            float e3 = __int_as_float(__builtin_amdgcn_readlane(evi, j + 3));
            float x0 = __half2float(zxh[(size_t)c0 * 128 + 64 + lane]);
            float x1 = __half2float(zxh[(size_t)c1 * 128 + 64 + lane]);
            float x2 = __half2float(zxh[(size_t)c2 * 128 + 64 + lane]);
            float x3 = __half2float(zxh[(size_t)c3 * 128 + 64 + lane]);
            acc = fmaf(e0, x0, acc);
            acc = fmaf(e1, x1, acc);
            acc = fmaf(e2, x2, acc);
            acc = fmaf(e3, x3, acc);
            dsum += (e0 + e1) + (e2 + e3);
        }
        for (; j < m; ++j) {
            int c0 = __builtin_amdgcn_readlane(cc, j);
            float e0 = __int_as_float(__builtin_amdgcn_readlane(evi, j));
            float x0 = __half2float(zxh[(size_t)c0 * 128 + 64 + lane]);
            acc = fmaf(e0, x0, acc);
            dsum += e0;
        }
    }
    float a = acc / (dsum + 1e-9f);
    float sres = bs[lane];
#pragma unroll
    for (int d = 0; d < 64; ++d) {
        sres = fmaf(__shfl(a, d), Wt[d * 65 + lane], sres);
    }
    out[n * D + lane] = sres;
}

extern "C" void kernel_launch(void* const* d_in, const int* in_sizes, int n_in,
                              void* d_out, int out_size, void* d_ws, size_t ws_size,
                              hipStream_t stream) {
    const float* x = (const float*)d_in[0];
    const int* ei = (const int*)d_in[1];  // [2, NE] int32
    const float* z = (const float*)d_in[2];
    const float* W = (const float*)d_in[3];
    const float* b = (const float*)d_in[4];
    const float* alpha = (const float*)d_in[5];
    const float* bias_edge = (const float*)d_in[6];
    float* out = (float*)d_out;  // [NN, D]

    // workspace layout
    char* ws = (char*)d_ws;
    size_t off = 0;
    __half* zxh = (__half*)(ws + off); off += (size_t)NN * 128 * 2;   // 25.6 MB
    int* colidx = (int*)(ws + off); off += (size_t)NE * 4;            // 6.4 MB
    int* rowidx = (int*)(ws + off); off += (size_t)NE * 4;            // 6.4 MB
    float* exv = (float*)(ws + off); off += (size_t)NE * 4;           // 6.4 MB
    int* cnt = (int*)(ws + off); off += (size_t)NN * 4;
    int* inc = (int*)(ws + off); off += (size_t)NN * 4;
    int* row_start = (int*)(ws + off); off += (size_t)NN * 4;
    int* cursor = (int*)(ws + off); off += (size_t)NN * 4;
    int* bsum = (int*)(ws + off); off += 512 * 4;

    k_prep<<<(NN * 64 + 255) / 256, 256, 0, stream>>>(z, x, zxh, cnt);
    k_count<<<2048, 256, 0, stream>>>(ei, cnt);
    k_scan1<<<NBLK, 256, 0, stream>>>(cnt, inc, bsum);
    k_scan2<<<1, 512, 0, stream>>>(bsum);
    k_scan3<<<NBLK, 256, 0, stream>>>(cnt, inc, bsum, row_start, cursor);
    k_place<<<2048, 256, 0, stream>>>(ei, cursor, colidx, rowidx);
    k_edges<<<(NE + 255) / 256, 256, 0, stream>>>(zxh, rowidx, colidx, alpha, bias_edge, exv);
    k_gather<<<(NN * 64 + 255) / 256, 256, 0, stream>>>(zxh, colidx, exv, row_start, cnt, W, b, out);
}